// Round 4
// baseline (866.072 us; speedup 1.0000x reference)
//
#include <hip/hip_runtime.h>
#include <hip/hip_bf16.h>
#include <hip/hip_cooperative_groups.h>

namespace cg = cooperative_groups;

#define NN 16384
#define NE 65536

typedef __attribute__((ext_vector_type(8))) short short8;
typedef __attribute__((ext_vector_type(4))) float f32x4;

using bf16 = __hip_bfloat16;

__device__ __forceinline__ float b2f(bf16 v){ return __bfloat162float(v); }
__device__ __forceinline__ bf16 f2b(float v){ return __float2bfloat16(v); }

struct MegaArgs {
    const float *x, *y, *rel, *a;
    const int *send, *recv;
    const float *W[4], *P[4];
    const float *bb[4], *bs[4], *bo[4], *bm[4], *bv[4];
    float* gC;               // [4][NN*32][16] tap weights in CSR slot order
    unsigned *curs, *csr, *epos;
    bf16 *h1, *xo, *h3, *Bp;
    float* outp;
};

// ---------------- phase 0: zero curs + pack W into MFMA B-fragment order ----
__device__ __forceinline__ void ph0(const MegaArgs& A){
    int gtid = blockIdx.x*256 + threadIdx.x;
    if(gtid < NN) A.curs[gtid] = 0u;
    if(gtid < 20480){
        int t = gtid;
        const float* W; int Cout; int base; int tl;
        if(t < 8192)      { W=A.W[0]; Cout=64; base=0;     tl=t; }
        else if(t < 12288){ W=A.W[1]; Cout=32; base=8192;  tl=t-8192; }
        else if(t < 16384){ W=A.W[2]; Cout=64; base=12288; tl=t-12288; }
        else              { W=A.W[3]; Cout=32; base=16384; tl=t-16384; }
        int l  = tl & 63;
        int NCT = Cout >> 4;
        int ct = (tl >> 6) % NCT;
        int ks = (tl >> 6) / NCT;
        int col = ct*16 + (l & 15);
        int k0  = ks*32 + ((l >> 4) & 3)*8;
        short8 v;
        #pragma unroll
        for(int j=0;j<8;j++){
            bf16 h = f2b(W[(size_t)(k0+j)*Cout + col]);
            v[j] = (short)*(unsigned short*)&h;
        }
        ((short8*)A.Bp)[base + tl] = v;
    }
}

// ---------------- phase 1: count + fill fixed-capacity CSR, record slot ----
__device__ __forceinline__ void ph1(const MegaArgs& A){
    int e = blockIdx.x*256 + threadIdx.x;
    if(e < NE){
        int rv = A.recv[e];
        unsigned pos = atomicAdd(&A.curs[rv], 1u);
        unsigned ep = 0xFFFFFFFFu;
        if(pos < 32u){
            ep = (unsigned)rv*32u + pos;
            A.csr[ep] = (unsigned)A.send[e];
        }
        A.epos[e] = ep;
    }
}

// ---------------- phase 2: tap softmax, scattered into CSR slot order ------
__device__ __forceinline__ void ph2(const MegaArgs& A){
    int gtid = blockIdx.x*256 + threadIdx.x;     // 262144 = NE*4 exactly
    int e = gtid >> 2, c = gtid & 3;
    float r0 = A.rel[e*3+0], r1 = A.rel[e*3+1], r2 = A.rel[e*3+2];
    float av = A.a[e];
    const float* P = A.P[c];
    float lg[16]; float mx = -1e30f;
    #pragma unroll
    for(int k=0;k<16;k++){
        float v = r0*P[k] + r1*P[16+k] + r2*P[32+k];
        lg[k] = v; mx = fmaxf(mx, v);
    }
    float ssum = 0.f;
    #pragma unroll
    for(int k=0;k<16;k++){ lg[k] = __expf(lg[k]-mx); ssum += lg[k]; }
    float inv = av/ssum;
    unsigned ep = A.epos[e];
    if(ep != 0xFFFFFFFFu){
        float* go = A.gC + ((size_t)c*(NN*32) + ep)*16;
        #pragma unroll
        for(int j=0;j<4;j++){
            ((float4*)go)[j] = make_float4(lg[j*4]*inv, lg[j*4+1]*inv,
                                           lg[j*4+2]*inv, lg[j*4+3]*inv);
        }
    }
}

// ---------------- fused conv phase: agg -> LDS tile -> MFMA -> epilogue ----
template<int CIN, int NCT, int MODE, bool CONCAT, typename OT>
__device__ __forceinline__ void conv_phase(
    char* sT, float* red,
    const void* fAv, const float* fBv,
    const float* gC,                          // conv slice, [node*32+j][16]
    const unsigned* csr, const unsigned* curs,
    const bf16* Bp, const float* bias,
    const float* bns, const float* bno,
    const float* bnm, const float* bnv,
    const float* x, const float* y, OT* out)
{
    constexpr int KD   = CIN*16;
    constexpr int ROWB = KD*2;
    int wv = threadIdx.x >> 6, lane = threadIdx.x & 63;
    int nbase = blockIdx.x*16;

    const float* fAf = (const float*)fAv;
    const bf16*  fAb = (const bf16*)fAv;
    const int i     = (CIN==64) ? lane : (lane & 31);
    const int kbase = (CIN==64) ? 0 : ((lane >> 5) * 8);
    for(int t=0; t<4; t++){
        int nl   = wv*4 + t;
        int node = nbase + nl;
        unsigned cnt = curs[node]; if(cnt > 32u) cnt = 32u;
        constexpr int KPL = (CIN==64) ? 16 : 8;
        float acc[KPL];
        #pragma unroll
        for(int r=0;r<KPL;r++) acc[r] = 0.f;
        const unsigned* crow = csr + (unsigned)node*32u;
        const float* gnode = gC + (size_t)node*32u*16u + kbase;
        for(unsigned j=0; j<cnt; j++){
            int sid = (int)crow[j];
            float fe;
            if(CONCAT){
                fe = (lane < 32) ? fAf[sid*32 + lane] : fBv[sid*32 + (lane-32)];
            } else {
                fe = b2f(fAb[sid*CIN + i]);
            }
            const float4* gp = (const float4*)(gnode + j*16);
            if(CIN==64){
                float4 g0=gp[0], g1=gp[1], g2=gp[2], g3=gp[3];
                acc[0]  += g0.x*fe; acc[1]  += g0.y*fe; acc[2]  += g0.z*fe; acc[3]  += g0.w*fe;
                acc[4]  += g1.x*fe; acc[5]  += g1.y*fe; acc[6]  += g1.z*fe; acc[7]  += g1.w*fe;
                acc[8]  += g2.x*fe; acc[9]  += g2.y*fe; acc[10] += g2.z*fe; acc[11] += g2.w*fe;
                acc[12] += g3.x*fe; acc[13] += g3.y*fe; acc[14] += g3.z*fe; acc[15] += g3.w*fe;
            } else {
                float4 g0=gp[0], g1=gp[1];
                acc[0] += g0.x*fe; acc[1] += g0.y*fe; acc[2] += g0.z*fe; acc[3] += g0.w*fe;
                acc[4] += g1.x*fe; acc[5] += g1.y*fe; acc[6] += g1.z*fe; acc[7] += g1.w*fe;
            }
        }
        unsigned xo_ = (unsigned)((nl & 7) << 4);
        if(CIN==64){
            #pragma unroll
            for(int k=0;k<16;k++){
                unsigned byte = (unsigned)nl*ROWB + ((((unsigned)(k*64 + lane))*2u) ^ xo_);
                *(bf16*)(sT + byte) = f2b(acc[k]);
            }
        } else {
            #pragma unroll
            for(int r=0;r<8;r++){
                unsigned byte = (unsigned)nl*ROWB + ((((unsigned)((kbase+r)*32 + i))*2u) ^ xo_);
                *(bf16*)(sT + byte) = f2b(acc[r]);
            }
        }
    }
    __syncthreads();

    // ---------- GEMM from LDS ----------
    int r = lane & 15, h = lane >> 4;
    const short8* Bp8 = (const short8*)Bp;
    f32x4 acc4 = (f32x4){0.f,0.f,0.f,0.f};
    int c, ks0, ksn;
    if(NCT==4){ c = wv;      ks0 = 0;                ksn = KD/32; }
    else      { c = wv & 1;  ks0 = (wv>>1)*(KD/64);  ksn = KD/64; }
    unsigned xr = (unsigned)((r & 7) << 4);
    #pragma unroll 8
    for(int ks=ks0; ks<ks0+ksn; ks++){
        unsigned ab = (unsigned)r*ROWB + (((unsigned)(ks*64 + h*16)) ^ xr);
        short8 af  = *(const short8*)(sT + ab);
        short8 bfr = Bp8[(ks*NCT + c)*64 + lane];
        acc4 = __builtin_amdgcn_mfma_f32_16x16x32_bf16(af, bfr, acc4, 0, 0, 0);
    }
    bool active = true;
    if(NCT==2){
        if(wv >= 2){
            #pragma unroll
            for(int j=0;j<4;j++) red[c*256 + (h*4+j)*16 + r] = acc4[j];
        }
        __syncthreads();
        if(wv >= 2) active = false;
        else {
            #pragma unroll
            for(int j=0;j<4;j++) acc4[j] += red[c*256 + (h*4+j)*16 + r];
        }
    }
    if(active){
        const int Cout = NCT*16;
        int col = c*16 + r;
        float inv = rsqrtf(bnv[col] + 1e-5f);
        float al  = bns[col] * inv;
        float be  = al*(bias[col] - bnm[col]) + bno[col];
        #pragma unroll
        for(int j=0;j<4;j++){
            int rr = nbase + h*4 + j;
            float v = al*acc4[j] + be;
            if(MODE==0){
                out[(size_t)rr*Cout + col] = (OT)fmaxf(v, 0.f);
            } else {
                float wei = 1.f/(1.f + __expf(-v));
                float xv = x[rr*32 + col];
                float yv = y[rr*32 + col];
                out[(size_t)rr*32 + col] = (OT)(2.f*xv*wei + 2.f*yv*(1.f - wei));
            }
        }
    }
}

__device__ __forceinline__ void run_c1(const MegaArgs& A, char* sT, float* red){
    conv_phase<64,4,0,true,bf16>(sT, red, A.x, A.y, A.gC,
        A.csr, A.curs, A.Bp, A.bb[0], A.bs[0], A.bo[0], A.bm[0], A.bv[0],
        nullptr, nullptr, A.h1);
}
__device__ __forceinline__ void run_c2(const MegaArgs& A, char* sT, float* red){
    conv_phase<64,2,1,false,bf16>(sT, red, A.h1, nullptr, A.gC + (size_t)1*NN*32*16,
        A.csr, A.curs, A.Bp + (size_t)8192*8, A.bb[1], A.bs[1], A.bo[1], A.bm[1], A.bv[1],
        A.x, A.y, A.xo);
}
__device__ __forceinline__ void run_c3(const MegaArgs& A, char* sT, float* red){
    conv_phase<32,4,0,false,bf16>(sT, red, A.xo, nullptr, A.gC + (size_t)2*NN*32*16,
        A.csr, A.curs, A.Bp + (size_t)12288*8, A.bb[2], A.bs[2], A.bo[2], A.bm[2], A.bv[2],
        nullptr, nullptr, A.h3);
}
__device__ __forceinline__ void run_c4(const MegaArgs& A, char* sT, float* red){
    conv_phase<64,2,1,false,float>(sT, red, A.h3, nullptr, A.gC + (size_t)3*NN*32*16,
        A.csr, A.curs, A.Bp + (size_t)16384*8, A.bb[3], A.bs[3], A.bo[3], A.bm[3], A.bv[3],
        A.x, A.y, A.outp);
}

// ---------------- the mega cooperative kernel ----------------
__global__ __launch_bounds__(256, 4) void k_mega(MegaArgs A){
    __shared__ __align__(16) char sT[32768];
    __shared__ float red[512];
    cg::grid_group g = cg::this_grid();
    ph0(A);  g.sync();
    ph1(A);  g.sync();
    ph2(A);  g.sync();
    run_c1(A, sT, red);  g.sync();
    run_c2(A, sT, red);  g.sync();
    run_c3(A, sT, red);  g.sync();
    run_c4(A, sT, red);
}

// ---------------- fallback wrappers (plain launches, same bodies) ----------
__global__ __launch_bounds__(256,4) void k_p0(MegaArgs A){ ph0(A); }
__global__ __launch_bounds__(256,4) void k_p1(MegaArgs A){ ph1(A); }
__global__ __launch_bounds__(256,4) void k_p2(MegaArgs A){ ph2(A); }
__global__ __launch_bounds__(256,4) void k_c1(MegaArgs A){
    __shared__ __align__(16) char sT[32768]; __shared__ float red[512];
    run_c1(A, sT, red);
}
__global__ __launch_bounds__(256,4) void k_c2(MegaArgs A){
    __shared__ __align__(16) char sT[32768]; __shared__ float red[512];
    run_c2(A, sT, red);
}
__global__ __launch_bounds__(256,4) void k_c3(MegaArgs A){
    __shared__ __align__(16) char sT[32768]; __shared__ float red[512];
    run_c3(A, sT, red);
}
__global__ __launch_bounds__(256,4) void k_c4(MegaArgs A){
    __shared__ __align__(16) char sT[32768]; __shared__ float red[512];
    run_c4(A, sT, red);
}

// ---------------- launch ----------------
extern "C" void kernel_launch(void* const* d_in, const int* in_sizes, int n_in,
                              void* d_out, int out_size, void* d_ws, size_t ws_size,
                              hipStream_t stream){
    MegaArgs A;
    A.x    = (const float*)d_in[0];
    A.y    = (const float*)d_in[1];
    A.send = (const int*)d_in[2];
    A.recv = (const int*)d_in[3];
    A.rel  = (const float*)d_in[4];
    A.a    = (const float*)d_in[5];
    for(int i=0;i<4;i++){
        int base = 6 + i*7;
        A.W[i]  = (const float*)d_in[base+0];
        A.P[i]  = (const float*)d_in[base+1];
        A.bb[i] = (const float*)d_in[base+2];
        A.bs[i] = (const float*)d_in[base+3];
        A.bo[i] = (const float*)d_in[base+4];
        A.bm[i] = (const float*)d_in[base+5];
        A.bv[i] = (const float*)d_in[base+6];
    }
    char* w = (char*)d_ws;
    A.gC   = (float*)(w);                      // 134,217,728 B
    A.curs = (unsigned*)(w + 134217728);       //      65,536 B
    A.csr  = (unsigned*)(w + 134283264);       //   2,097,152 B
    A.epos = (unsigned*)(w + 136380416);       //     262,144 B
    A.h1   = (bf16*)(w + 136642560);           //   2,097,152 B
    A.xo   = (bf16*)(w + 138739712);           //   1,048,576 B
    A.h3   = (bf16*)(w + 139788288);           //   2,097,152 B
    A.Bp   = (bf16*)(w + 141885440);           //     327,680 B
    A.outp = (float*)d_out;

    void* kp[1] = { (void*)&A };
    hipError_t err = hipLaunchCooperativeKernel((const void*)k_mega,
                                                dim3(1024), dim3(256), kp, 0, stream);
    if(err != hipSuccess){
        (void)hipGetLastError();   // clear, fall back to plain launches
        k_p0<<<1024, 256, 0, stream>>>(A);
        k_p1<<<1024, 256, 0, stream>>>(A);
        k_p2<<<1024, 256, 0, stream>>>(A);
        k_c1<<<1024, 256, 0, stream>>>(A);
        k_c2<<<1024, 256, 0, stream>>>(A);
        k_c3<<<1024, 256, 0, stream>>>(A);
        k_c4<<<1024, 256, 0, stream>>>(A);
    }
}

// Round 5
// 98.336 us; speedup vs baseline: 8.8073x; 8.8073x over previous
//
#include <hip/hip_runtime.h>
#include <hip/hip_bf16.h>

#define NN 16384
#define NE 65536

typedef __attribute__((ext_vector_type(8))) short short8;
typedef __attribute__((ext_vector_type(4))) float f32x4;

using bf16 = __hip_bfloat16;

__device__ __forceinline__ float b2f(bf16 v){ return __bfloat162float(v); }
__device__ __forceinline__ bf16 f2b(float v){ return __float2bfloat16(v); }

// ================= k_init: zero curs | tap weights g | pack W =================
// blocks [0,64): zero curs ; [64,320): g (e-indexed) ; [320,400): W pack
__global__ __launch_bounds__(256) void k_init(
    unsigned* __restrict__ curs,
    const float* __restrict__ rel, const float* __restrict__ a,
    const float* __restrict__ P1, const float* __restrict__ P2,
    const float* __restrict__ P3, const float* __restrict__ P4,
    float* __restrict__ g,
    const float* __restrict__ W1, const float* __restrict__ W2,
    const float* __restrict__ W3, const float* __restrict__ W4,
    bf16* __restrict__ Bp)
{
    int b = blockIdx.x;
    if(b < 64){
        curs[b*256 + threadIdx.x] = 0u;
        return;
    }
    if(b < 320){
        int e = (b-64)*256 + threadIdx.x;
        float r0 = rel[e*3+0], r1 = rel[e*3+1], r2 = rel[e*3+2];
        float av = a[e];
        const float* Ps[4] = {P1,P2,P3,P4};
        for(int c=0;c<4;c++){
            const float* P = Ps[c];
            float lg[16]; float mx = -1e30f;
            #pragma unroll
            for(int k=0;k<16;k++){
                float v = r0*P[k] + r1*P[16+k] + r2*P[32+k];
                lg[k] = v; mx = fmaxf(mx, v);
            }
            float ssum = 0.f;
            #pragma unroll
            for(int k=0;k<16;k++){ lg[k] = __expf(lg[k]-mx); ssum += lg[k]; }
            float inv = av/ssum;
            float* go = &g[((size_t)c*NE + e)*16];
            #pragma unroll
            for(int j=0;j<4;j++){
                ((float4*)go)[j] = make_float4(lg[j*4]*inv, lg[j*4+1]*inv,
                                               lg[j*4+2]*inv, lg[j*4+3]*inv);
            }
        }
        return;
    }
    // ---- W pack into MFMA B-fragment order ----
    int t = (b-320)*256 + threadIdx.x;
    const float* W; int Cout; int base; int tl;
    if(t < 8192)      { W=W1; Cout=64; base=0;     tl=t; }
    else if(t < 12288){ W=W2; Cout=32; base=8192;  tl=t-8192; }
    else if(t < 16384){ W=W3; Cout=64; base=12288; tl=t-12288; }
    else              { W=W4; Cout=32; base=16384; tl=t-16384; }
    int l  = tl & 63;
    int NCT = Cout >> 4;
    int ct = (tl >> 6) % NCT;
    int ks = (tl >> 6) / NCT;
    int col = ct*16 + (l & 15);
    int k0  = ks*32 + ((l >> 4) & 3)*8;
    short8 v;
    #pragma unroll
    for(int j=0;j<8;j++){
        bf16 h = f2b(W[(size_t)(k0+j)*Cout + col]);
        v[j] = (short)*(unsigned short*)&h;
    }
    ((short8*)Bp)[base + tl] = v;
}

// ================= k_countfill: fixed-capacity buckets, value=(eid<<14|sid) ===
__global__ __launch_bounds__(256) void k_countfill(const int* __restrict__ recv,
                                                   const int* __restrict__ send,
                                                   unsigned* __restrict__ curs,
                                                   unsigned* __restrict__ csr){
    int e = blockIdx.x*256 + threadIdx.x;
    if(e >= NE) return;
    int rv = recv[e];
    unsigned pos = atomicAdd(&curs[rv], 1u);
    if(pos < 32u) csr[(unsigned)rv*32u + pos] = ((unsigned)e << 14) | (unsigned)send[e];
}

// ================= fused conv: wave-per-node agg -> LDS -> MFMA -> epilogue ===
// Block: 1024 threads = 16 waves = 16 nodes. Wave wv aggregates node nbase+wv
// with an 8-deep unrolled predicated edge loop (full MLP), writes its bf16 row
// to LDS with XOR swizzle, then waves 0..NCT-1 run the 16xCout GEMM (full K).
template<int CIN, int NCT, int MODE, bool CONCAT, typename OT>
__global__ __launch_bounds__(1024, 4) void k_conv(
    const void* __restrict__ fAv, const float* __restrict__ fBv,
    const float* __restrict__ g,
    const unsigned* __restrict__ csr, const unsigned* __restrict__ curs,
    const bf16* __restrict__ Bp, const float* __restrict__ bias,
    const float* __restrict__ bns, const float* __restrict__ bno,
    const float* __restrict__ bnm, const float* __restrict__ bnv,
    const float* __restrict__ x, const float* __restrict__ y,
    OT* __restrict__ out)
{
    constexpr int KD   = CIN*16;
    constexpr int ROWB = KD*2;
    __shared__ __align__(16) char sT[16*ROWB];
    int wv = threadIdx.x >> 6, lane = threadIdx.x & 63;
    int nbase = blockIdx.x*16;
    int node  = nbase + wv;
    int nl    = wv;

    // ---------- aggregation (one node per wave) ----------
    const float* fAf = (const float*)fAv;
    const bf16*  fAb = (const bf16*)fAv;
    const int i     = (CIN==64) ? lane : (lane & 31);
    const int kbase = (CIN==64) ? 0 : ((lane >> 5) * 8);
    unsigned cnt = curs[node]; if(cnt > 32u) cnt = 32u;
    const unsigned* crow = csr + (unsigned)node*32u;
    uint4 ca = ((const uint4*)crow)[0];
    uint4 cb = ((const uint4*)crow)[1];
    unsigned uu[8] = {ca.x, ca.y, ca.z, ca.w, cb.x, cb.y, cb.z, cb.w};

    constexpr int KPL = (CIN==64) ? 16 : 8;
    float acc[KPL];
    #pragma unroll
    for(int r=0;r<KPL;r++) acc[r] = 0.f;

    auto edge = [&](unsigned u){
        int sid = (int)(u & 16383u);
        int eid = (int)(u >> 14);
        float fe;
        if(CONCAT){
            fe = (lane < 32) ? fAf[sid*32 + lane] : fBv[sid*32 + (lane-32)];
        } else {
            fe = b2f(fAb[sid*CIN + i]);
        }
        const float4* gp = (const float4*)&g[(size_t)eid*16 + kbase];
        if(CIN==64){
            float4 g0=gp[0], g1=gp[1], g2=gp[2], g3=gp[3];
            acc[0]  += g0.x*fe; acc[1]  += g0.y*fe; acc[2]  += g0.z*fe; acc[3]  += g0.w*fe;
            acc[4]  += g1.x*fe; acc[5]  += g1.y*fe; acc[6]  += g1.z*fe; acc[7]  += g1.w*fe;
            acc[8]  += g2.x*fe; acc[9]  += g2.y*fe; acc[10] += g2.z*fe; acc[11] += g2.w*fe;
            acc[12] += g3.x*fe; acc[13] += g3.y*fe; acc[14] += g3.z*fe; acc[15] += g3.w*fe;
        } else {
            float4 g0=gp[0], g1=gp[1];
            acc[0] += g0.x*fe; acc[1] += g0.y*fe; acc[2] += g0.z*fe; acc[3] += g0.w*fe;
            acc[4] += g1.x*fe; acc[5] += g1.y*fe; acc[6] += g1.z*fe; acc[7] += g1.w*fe;
        }
    };
    #pragma unroll
    for(int j=0;j<8;j++){
        if((unsigned)j < cnt) edge(uu[j]);
    }
    for(unsigned j=8; j<cnt; j++) edge(crow[j]);

    // ---------- LDS write (swizzled) ----------
    unsigned xo_ = (unsigned)((nl & 7) << 4);
    if(CIN==64){
        #pragma unroll
        for(int k=0;k<16;k++){
            unsigned byte = (unsigned)nl*ROWB + ((((unsigned)(k*64 + lane))*2u) ^ xo_);
            *(bf16*)(sT + byte) = f2b(acc[k]);
        }
    } else {
        #pragma unroll
        for(int r=0;r<8;r++){
            unsigned byte = (unsigned)nl*ROWB + ((((unsigned)((kbase+r)*32 + i))*2u) ^ xo_);
            *(bf16*)(sT + byte) = f2b(acc[r]);
        }
    }
    __syncthreads();

    // ---------- GEMM from LDS (waves 0..NCT-1, full K) ----------
    if(wv >= NCT) return;
    int r = lane & 15, h = lane >> 4;
    int c = wv;
    const short8* Bp8 = (const short8*)Bp;
    f32x4 acc4 = (f32x4){0.f,0.f,0.f,0.f};
    unsigned xr = (unsigned)((r & 7) << 4);
    #pragma unroll 8
    for(int ks=0; ks<KD/32; ks++){
        unsigned ab = (unsigned)r*ROWB + (((unsigned)(ks*64 + h*16)) ^ xr);
        short8 af  = *(const short8*)(sT + ab);
        short8 bfr = Bp8[(ks*NCT + c)*64 + lane];
        acc4 = __builtin_amdgcn_mfma_f32_16x16x32_bf16(af, bfr, acc4, 0, 0, 0);
    }

    // ---------- epilogue ----------
    const int Cout = NCT*16;
    int col = c*16 + r;
    float inv = rsqrtf(bnv[col] + 1e-5f);
    float al  = bns[col] * inv;
    float be  = al*(bias[col] - bnm[col]) + bno[col];
    #pragma unroll
    for(int j=0;j<4;j++){
        int rr = nbase + h*4 + j;
        float v = al*acc4[j] + be;
        if(MODE==0){
            out[(size_t)rr*Cout + col] = (OT)fmaxf(v, 0.f);
        } else {
            float wei = 1.f/(1.f + __expf(-v));
            float xv = x[rr*32 + col];
            float yv = y[rr*32 + col];
            out[(size_t)rr*32 + col] = (OT)(2.f*xv*wei + 2.f*yv*(1.f - wei));
        }
    }
}

// ================= launch =================
extern "C" void kernel_launch(void* const* d_in, const int* in_sizes, int n_in,
                              void* d_out, int out_size, void* d_ws, size_t ws_size,
                              hipStream_t stream){
    const float* x   = (const float*)d_in[0];
    const float* y   = (const float*)d_in[1];
    const int* send  = (const int*)d_in[2];
    const int* recv  = (const int*)d_in[3];
    const float* rel = (const float*)d_in[4];
    const float* a   = (const float*)d_in[5];
    const float *W[4], *P[4], *bb[4], *bs[4], *bo[4], *bm[4], *bv[4];
    for(int i=0;i<4;i++){
        int base = 6 + i*7;
        W[i]  = (const float*)d_in[base+0];
        P[i]  = (const float*)d_in[base+1];
        bb[i] = (const float*)d_in[base+2];
        bs[i] = (const float*)d_in[base+3];
        bo[i] = (const float*)d_in[base+4];
        bm[i] = (const float*)d_in[base+5];
        bv[i] = (const float*)d_in[base+6];
    }
    char* w = (char*)d_ws;
    float*    g    = (float*)(w);                   // 16,777,216 B
    unsigned* curs = (unsigned*)(w + 16777216);     //     65,536 B
    unsigned* csr  = (unsigned*)(w + 16842752);     //  2,097,152 B
    bf16*     h1   = (bf16*)(w + 18939904);         //  2,097,152 B
    bf16*     xo   = (bf16*)(w + 21037056);         //  1,048,576 B
    bf16*     h3   = (bf16*)(w + 22085632);         //  2,097,152 B
    bf16*     Bp   = (bf16*)(w + 24182784);         //    327,680 B
    float*    outp = (float*)d_out;

    k_init     <<<400, 256, 0, stream>>>(curs, rel, a, P[0], P[1], P[2], P[3], g,
                                         W[0], W[1], W[2], W[3], Bp);
    k_countfill<<<NE/256, 256, 0, stream>>>(recv, send, curs, csr);

    // conv1: [x|y] -> h1 (BN+relu)
    (k_conv<64,4,0,true,bf16>)  <<<NN/16, 1024, 0, stream>>>(x, y, g + (size_t)0*NE*16, csr, curs,
        Bp + (size_t)0*8,     bb[0], bs[0], bo[0], bm[0], bv[0], nullptr, nullptr, h1);
    // conv2: h1 -> wei1 -> xo (AFF)
    (k_conv<64,2,1,false,bf16>) <<<NN/16, 1024, 0, stream>>>(h1, nullptr, g + (size_t)1*NE*16, csr, curs,
        Bp + (size_t)8192*8,  bb[1], bs[1], bo[1], bm[1], bv[1], x, y, xo);
    // conv3: xo -> h3 (BN+relu)
    (k_conv<32,4,0,false,bf16>) <<<NN/16, 1024, 0, stream>>>(xo, nullptr, g + (size_t)2*NE*16, csr, curs,
        Bp + (size_t)12288*8, bb[2], bs[2], bo[2], bm[2], bv[2], nullptr, nullptr, h3);
    // conv4: h3 -> wei2 -> out (AFF, f32)
    (k_conv<64,2,1,false,float>)<<<NN/16, 1024, 0, stream>>>(h3, nullptr, g + (size_t)3*NE*16, csr, curs,
        Bp + (size_t)16384*8, bb[3], bs[3], bo[3], bm[3], bv[3], x, y, outp);
}